// Round 11
// baseline (952.738 us; speedup 1.0000x reference)
//
#include <hip/hip_runtime.h>
#include <math.h>

// Problem constants (match reference)
#define NN 20000
#define T_IN 8
#define FEAT 16
#define HID 128
#define H3 384
#define FUSER_IN 49
#define FUSER_H 96
#define GATE_H 48
#define ALPHA 0.5f

typedef unsigned short u16;
typedef __attribute__((ext_vector_type(8))) short bf16x8_t;
typedef __attribute__((ext_vector_type(4))) float f32x4_t;

__device__ __forceinline__ float sigmoidf_(float v) { return 1.0f / (1.0f + expf(-v)); }

// bf16 round-to-nearest-even (finite values only)
__device__ __forceinline__ u16 f2b(float v) {
    unsigned u = __float_as_uint(v);
    unsigned r = (u + 0x7fffu + ((u >> 16) & 1u)) >> 16;
    return (u16)r;
}
__device__ __forceinline__ float b2f(u16 u) { return __uint_as_float(((unsigned)u) << 16); }

// ---------------- preprocessing ----------------

__global__ void init_kernel(int* first_eid, int* deg_cnt, int* gcount, int n) {
    int i = blockIdx.x * 256 + threadIdx.x;
    if (i < n) { first_eid[i] = 0x7fffffff; deg_cnt[i] = 0; }
    if (i == 0) *gcount = 0;
}

__global__ void edge_pass1(const int* __restrict__ src, const int* __restrict__ dst,
                           int* first_eid, int* deg_cnt, int e) {
    int i = blockIdx.x * 256 + threadIdx.x;
    if (i < e) {
        atomicMin(&first_eid[src[i]], i);
        atomicAdd(&deg_cnt[dst[i]], 1);
    }
}

// 3-phase parallel prefix sum over cnt[n] (n <= 256*256)
__global__ void scan1(const int* __restrict__ cnt, int* tmp, int* bsum, int n) {
    __shared__ int buf[256];
    int tid = threadIdx.x;
    int i = blockIdx.x * 256 + tid;
    int v = (i < n) ? cnt[i] : 0;
    buf[tid] = v;
    __syncthreads();
    #pragma unroll
    for (int off = 1; off < 256; off <<= 1) {
        int t = (tid >= off) ? buf[tid - off] : 0;
        __syncthreads();
        buf[tid] += t;
        __syncthreads();
    }
    if (i < n) tmp[i] = buf[tid];
    if (tid == 255) bsum[blockIdx.x] = buf[255];
}

__global__ void scan2(int* bsum, int nb) {
    __shared__ int buf[256];
    int tid = threadIdx.x;
    int v = (tid < nb) ? bsum[tid] : 0;
    buf[tid] = v;
    __syncthreads();
    #pragma unroll
    for (int off = 1; off < 256; off <<= 1) {
        int t = (tid >= off) ? buf[tid - off] : 0;
        __syncthreads();
        buf[tid] += t;
        __syncthreads();
    }
    if (tid < nb) bsum[tid] = buf[tid];   // inclusive block sums
}

__global__ void scan3(const int* __restrict__ cnt, const int* __restrict__ tmp,
                      const int* __restrict__ bsum,
                      int* row_ptr, int* fill_ptr, float* dis, float* norm_self, int n) {
    int i = blockIdx.x * 256 + threadIdx.x;
    if (i >= n) return;
    int pre = (blockIdx.x > 0) ? bsum[blockIdx.x - 1] : 0;
    int incl = tmp[i] + pre;
    int v = cnt[i];
    row_ptr[i + 1] = incl;
    fill_ptr[i] = incl - v;
    float deg = (float)v + 1.0f;
    dis[i] = 1.0f / sqrtf(deg);
    norm_self[i] = 1.0f / deg;
    if (i == 0) row_ptr[0] = 0;
}

__global__ void firsts_kernel(const int* __restrict__ first_eid, const int* __restrict__ dst,
                              const float* __restrict__ edge_attr,
                              int* first_out, float* first_dx, int n, int e) {
    int i = blockIdx.x * 256 + threadIdx.x;
    if (i >= n) return;
    int fe = first_eid[i];
    if (fe < e) {
        first_out[i] = dst[fe];
        first_dx[i] = fmaxf(edge_attr[fe], 1e-6f);
    } else {
        first_out[i] = -1;
        first_dx[i] = -1.0f;
    }
}

__global__ void edge_pass2(const int* __restrict__ src, const int* __restrict__ dst,
                           int* fill_ptr, const float* __restrict__ dis,
                           int* csr_src, float* csr_w, int e) {
    int i = blockIdx.x * 256 + threadIdx.x;
    if (i < e) {
        int d = dst[i], s = src[i];
        int pos = atomicAdd(&fill_ptr[d], 1);
        csr_src[pos] = s;
        csr_w[pos] = dis[s] * dis[d];
    }
}

// ghost prep + compaction: ghost_pos[node] = slot or -1; ghost_list[slot] = node
__global__ void ghost_kernel(const int* __restrict__ mask, const int* __restrict__ first_out,
                             const float* __restrict__ first_dx,
                             int* d1_of, int* d2_of, float* dxb_of,
                             int* ghost_list, int* ghost_pos, int* gcount, int n) {
    int i = blockIdx.x * 256 + threadIdx.x;
    if (i >= n) return;
    if (mask[i] != 0) { ghost_pos[i] = -1; return; }
    int pos = atomicAdd(gcount, 1);
    ghost_list[pos] = i;
    ghost_pos[i] = pos;
    int b = first_out[i];
    float dxb = fmaxf(first_dx[i], 1e-6f);
    int d1, d2;
    if (b < 0) { d1 = i; d2 = i; }
    else {
        int n1 = first_out[b]; d1 = (n1 < 0) ? b : n1;
        int n2 = first_out[d1]; d2 = (n2 < 0) ? d1 : n2;
    }
    d1_of[i] = d1; d2_of[i] = d2; dxb_of[i] = dxb;
}

// zero two regions in one dispatch (grid-stride)
__global__ void zero2_kernel(float* a, int na, unsigned* b, int nb) {
    int stride = gridDim.x * 256;
    for (int i = blockIdx.x * 256 + threadIdx.x; i < na; i += stride) a[i] = 0.0f;
    for (int i = blockIdx.x * 256 + threadIdx.x; i < nb; i += stride) b[i] = 0u;
}

// W[k][nn] (K=128) -> BT_hi/BT_lo[nn][k] bf16 split, LDS-tiled transpose (coalesced both sides)
__global__ __launch_bounds__(256)
void wsplit_kernel(const float* __restrict__ W, u16* BT_hi, u16* BT_lo, int Ncols) {
    __shared__ float tile[32][33];
    int nb = blockIdx.x * 32;           // column-of-W (=row-of-BT) base
    int kb = blockIdx.y * 32;           // k base
    int tx = threadIdx.x & 31, ty = threadIdx.x >> 5;   // 32 x 8
    #pragma unroll
    for (int r = 0; r < 32; r += 8)
        tile[ty + r][tx] = W[(size_t)(kb + ty + r) * Ncols + nb + tx];
    __syncthreads();
    #pragma unroll
    for (int r = 0; r < 32; r += 8) {
        float v = tile[tx][ty + r];     // = W[kb+tx][nb+ty+r]
        u16 h = f2b(v);
        size_t off = (size_t)(nb + ty + r) * 128 + kb + tx;
        BT_hi[off] = h;
        BT_lo[off] = f2b(v - b2f(h));
    }
}

// ---------------- batched front-end kernels ----------------

// Ghost fusion only: blockIdx.x = ghost slot (exit if >= gcount), blockIdx.y = t.
__global__ __launch_bounds__(128)
void fuse_ghost(const float* __restrict__ x,
                const int* __restrict__ ghost_list, const int* __restrict__ gcount,
                const int* __restrict__ d1_of, const int* __restrict__ d2_of,
                const float* __restrict__ dxb_of,
                const float* __restrict__ Wf1, const float* __restrict__ bf1,
                const float* __restrict__ Wf2, const float* __restrict__ bf2,
                const float* __restrict__ Wg1, const float* __restrict__ bg1,
                const float* __restrict__ Wg2, const float* __restrict__ bg2,
                float* __restrict__ xf_buf) {
    int slot = blockIdx.x;
    if (slot >= *gcount) return;
    int t = blockIdx.y;
    int i = ghost_list[slot];
    int j = threadIdx.x;
    __shared__ float feats[FUSER_IN];
    __shared__ float z1[FUSER_H];
    __shared__ float zg[GATE_H];
    __shared__ float s_gate;

    if (j < FEAT) {
        int d1 = d1_of[i], d2 = d2_of[i];
        feats[j]            = x[((size_t)i * T_IN + t) * FEAT + j];
        feats[FEAT + j]     = x[((size_t)d1 * T_IN + t) * FEAT + j];
        feats[2 * FEAT + j] = x[((size_t)d2 * T_IN + t) * FEAT + j];
    }
    if (j == 0) feats[3 * FEAT] = dxb_of[i];
    __syncthreads();
    if (j < FUSER_H) {
        float acc = bf1[j];
        for (int k = 0; k < FUSER_IN; ++k) acc = fmaf(feats[k], Wf1[k * FUSER_H + j], acc);
        z1[j] = fmaxf(acc, 0.0f);
    }
    if (j < GATE_H) {
        float acc = bg1[j];
        for (int k = 0; k < FUSER_IN; ++k) acc = fmaf(feats[k], Wg1[k * GATE_H + j], acc);
        zg[j] = fmaxf(acc, 0.0f);
    }
    __syncthreads();
    if (j == 0) {
        float s = bg2[0];
        for (int k = 0; k < GATE_H; ++k) s = fmaf(zg[k], Wg2[k], s);
        s_gate = sigmoidf_(s);
    }
    __syncthreads();
    if (j < FEAT) {
        float acc = bf2[j];
        for (int k = 0; k < FUSER_H; ++k) acc = fmaf(z1[k], Wf2[k * FEAT + j], acc);
        xf_buf[((size_t)slot * T_IN + t) * FEAT + j] = feats[j] + ALPHA * acc * s_gate;
    }
}

// g = relu(xf @ W_lin + b_lin) for ALL (t,node) pairs. Grid-stride, 2 pairs/block,
// W_lin+b_lin cached in LDS. Output g8[t][node][128] bf16 hi/lo.
__global__ __launch_bounds__(256)
void lin_all(const float* __restrict__ x, const float* __restrict__ xf_buf,
             const int* __restrict__ ghost_pos,
             const float* __restrict__ W_lin, const float* __restrict__ b_lin,
             u16* __restrict__ g8_hi, u16* __restrict__ g8_lo, int n, int total) {
    __shared__ float Wl[FEAT][HID];
    __shared__ float bl[HID];
    #pragma unroll
    for (int k8 = 0; k8 < 8; ++k8) {
        int idx = threadIdx.x + k8 * 256;
        Wl[idx >> 7][idx & 127] = W_lin[idx];
    }
    if (threadIdx.x < HID) bl[threadIdx.x] = b_lin[threadIdx.x];
    __syncthreads();
    int j = threadIdx.x & 127;
    for (int pair = blockIdx.x * 2 + (threadIdx.x >> 7); pair < total; pair += gridDim.x * 2) {
        int node = pair % n;
        int t = pair / n;
        int gp = ghost_pos[node];
        const float* xr = (gp >= 0) ? &xf_buf[((size_t)gp * T_IN + t) * FEAT]
                                    : &x[((size_t)node * T_IN + t) * FEAT];
        float acc = bl[j];
        #pragma unroll
        for (int k = 0; k < FEAT; ++k) acc = fmaf(xr[k], Wl[k][j], acc);
        float v = fmaxf(acc, 0.0f);
        u16 hv = f2b(v);
        size_t off = (size_t)pair * HID + j;
        g8_hi[off] = hv;
        g8_lo[off] = f2b(v - b2f(hv));
    }
}

// Batched GCN GEMM: Cb[t][M x 128] = bf16(A[t] @ B), bf16x3 MFMA. BM=64, blockIdx.z = t.
__global__ __launch_bounds__(256)
void gemm_gcn_b(const u16* __restrict__ Ahi0, const u16* __restrict__ Alo0,
                const u16* __restrict__ BThi, const u16* __restrict__ BTlo,
                u16* __restrict__ Cb0, int M) {
    constexpr int BM = 64;
    __shared__ u16 ldsA[2][BM * 128];
    const size_t tOff = (size_t)blockIdx.z * M * 128;
    const u16* Ahi = Ahi0 + tOff;
    const u16* Alo = Alo0 + tOff;
    u16*       Cb  = Cb0 + tOff;

    const int tid  = threadIdx.x;
    const int row0 = blockIdx.x * BM;
    constexpr int MF = BM / 32;

    #pragma unroll
    for (int it = 0; it < BM / 16; ++it) {
        int unit = tid + it * 256;
        int r = unit >> 4, s = unit & 15;
        int gr = row0 + r;
        uint4 vh = make_uint4(0, 0, 0, 0), vl = vh;
        if (gr < M) {
            vh = *reinterpret_cast<const uint4*>(&Ahi[(size_t)gr * 128 + s * 8]);
            vl = *reinterpret_cast<const uint4*>(&Alo[(size_t)gr * 128 + s * 8]);
        }
        int byte = (r * 256 + s * 16) ^ ((r & 7) << 4);
        *reinterpret_cast<uint4*>((char*)(&ldsA[0][0]) + byte) = vh;
        *reinterpret_cast<uint4*>((char*)(&ldsA[1][0]) + byte) = vl;
    }
    __syncthreads();

    const int wid  = tid >> 6;
    const int lane = tid & 63;
    const int wr = (wid >> 1) * (BM / 2);
    const int wc = (wid & 1) * 64;
    const int l15 = lane & 15;
    const int lkh = lane >> 4;

    f32x4_t acc[MF][4] = {};

    #pragma unroll
    for (int kb = 0; kb < 4; ++kb) {
        bf16x8_t ah[MF], al[MF], bh[4], bl[4];
        #pragma unroll
        for (int m = 0; m < MF; ++m) {
            int row = wr + m * 16 + l15;
            int byte = (row * 256 + kb * 64 + lkh * 16) ^ ((row & 7) << 4);
            ah[m] = *reinterpret_cast<const bf16x8_t*>((const char*)(&ldsA[0][0]) + byte);
            al[m] = *reinterpret_cast<const bf16x8_t*>((const char*)(&ldsA[1][0]) + byte);
        }
        #pragma unroll
        for (int nf = 0; nf < 4; ++nf) {
            int col = wc + nf * 16 + l15;
            size_t off = (size_t)col * 128 + kb * 32 + lkh * 8;
            bh[nf] = *reinterpret_cast<const bf16x8_t*>(&BThi[off]);
            bl[nf] = *reinterpret_cast<const bf16x8_t*>(&BTlo[off]);
        }
        #pragma unroll
        for (int m = 0; m < MF; ++m)
            #pragma unroll
            for (int nf = 0; nf < 4; ++nf) {
                acc[m][nf] = __builtin_amdgcn_mfma_f32_16x16x32_bf16(ah[m], bh[nf], acc[m][nf], 0, 0, 0);
                acc[m][nf] = __builtin_amdgcn_mfma_f32_16x16x32_bf16(ah[m], bl[nf], acc[m][nf], 0, 0, 0);
                acc[m][nf] = __builtin_amdgcn_mfma_f32_16x16x32_bf16(al[m], bh[nf], acc[m][nf], 0, 0, 0);
            }
    }

    #pragma unroll
    for (int m = 0; m < MF; ++m) {
        int rbase = row0 + wr + m * 16 + lkh * 4;
        #pragma unroll
        for (int nf = 0; nf < 4; ++nf) {
            int col = wc + nf * 16 + l15;
            #pragma unroll
            for (int r2 = 0; r2 < 4; ++r2) {
                int row = rbase + r2;
                if (row < M) Cb[(size_t)row * 128 + col] = f2b(acc[m][nf][r2]);
            }
        }
    }
}

// Batched GCN aggregate over (half, node-block, t). Column-halved so each (t,half)
// working set = n*64*2B = 2.56 MB < 4 MiB XCD L2. t in low 3 bits (XCD affinity),
// half-major ordering (all half-0 blocks dispatch first). 16 lanes/node, ushort4.
__global__ __launch_bounds__(256)
void gcn_agg_b(const u16* __restrict__ hwb0,
               const int* __restrict__ row_ptr,
               const int* __restrict__ csr_src, const float* __restrict__ csr_w,
               const float* __restrict__ norm_self, const float* __restrict__ bias,
               u16* __restrict__ g_hi0, u16* __restrict__ g_lo0, int n, int nblk) {
    int bid = blockIdx.x;
    int t = bid & 7;
    int q = bid >> 3;
    int blk = q % nblk;
    int half = q / nblk;
    int node = blk * 16 + (threadIdx.x >> 4);
    int lane = threadIdx.x & 15;
    if (node >= n) return;
    const size_t tOff = (size_t)t * n * 128;
    const u16* hwb = hwb0 + tOff;
    u16* g_hi = g_hi0 + tOff;
    u16* g_lo = g_lo0 + tOff;
    const int cb = half * 64 + lane * 4;

    ushort4 sv = *reinterpret_cast<const ushort4*>(&hwb[(size_t)node * HID + cb]);
    float ns = norm_self[node];
    float4 a0, a1, a2, a3;
    a0.x = b2f(sv.x) * ns; a0.y = b2f(sv.y) * ns; a0.z = b2f(sv.z) * ns; a0.w = b2f(sv.w) * ns;
    a1 = make_float4(0.f, 0.f, 0.f, 0.f); a2 = a1; a3 = a1;
    int p  = row_ptr[node];
    int p1 = row_ptr[node + 1];
    for (; p + 4 <= p1; p += 4) {
        int s0 = csr_src[p], s1 = csr_src[p + 1], s2 = csr_src[p + 2], s3 = csr_src[p + 3];
        float w0 = csr_w[p], w1 = csr_w[p + 1], w2 = csr_w[p + 2], w3 = csr_w[p + 3];
        ushort4 v0 = *reinterpret_cast<const ushort4*>(&hwb[(size_t)s0 * HID + cb]);
        ushort4 v1 = *reinterpret_cast<const ushort4*>(&hwb[(size_t)s1 * HID + cb]);
        ushort4 v2 = *reinterpret_cast<const ushort4*>(&hwb[(size_t)s2 * HID + cb]);
        ushort4 v3 = *reinterpret_cast<const ushort4*>(&hwb[(size_t)s3 * HID + cb]);
        a0.x = fmaf(b2f(v0.x), w0, a0.x); a0.y = fmaf(b2f(v0.y), w0, a0.y);
        a0.z = fmaf(b2f(v0.z), w0, a0.z); a0.w = fmaf(b2f(v0.w), w0, a0.w);
        a1.x = fmaf(b2f(v1.x), w1, a1.x); a1.y = fmaf(b2f(v1.y), w1, a1.y);
        a1.z = fmaf(b2f(v1.z), w1, a1.z); a1.w = fmaf(b2f(v1.w), w1, a1.w);
        a2.x = fmaf(b2f(v2.x), w2, a2.x); a2.y = fmaf(b2f(v2.y), w2, a2.y);
        a2.z = fmaf(b2f(v2.z), w2, a2.z); a2.w = fmaf(b2f(v2.w), w2, a2.w);
        a3.x = fmaf(b2f(v3.x), w3, a3.x); a3.y = fmaf(b2f(v3.y), w3, a3.y);
        a3.z = fmaf(b2f(v3.z), w3, a3.z); a3.w = fmaf(b2f(v3.w), w3, a3.w);
    }
    for (; p < p1; ++p) {
        int s = csr_src[p];
        float w = csr_w[p];
        ushort4 v = *reinterpret_cast<const ushort4*>(&hwb[(size_t)s * HID + cb]);
        a0.x = fmaf(b2f(v.x), w, a0.x); a0.y = fmaf(b2f(v.y), w, a0.y);
        a0.z = fmaf(b2f(v.z), w, a0.z); a0.w = fmaf(b2f(v.w), w, a0.w);
    }
    float4 b4 = reinterpret_cast<const float4*>(bias)[half * 16 + lane];
    float ox = fmaxf(a0.x + a1.x + a2.x + a3.x + b4.x, 0.0f);
    float oy = fmaxf(a0.y + a1.y + a2.y + a3.y + b4.y, 0.0f);
    float oz = fmaxf(a0.z + a1.z + a2.z + a3.z + b4.z, 0.0f);
    float ow = fmaxf(a0.w + a1.w + a2.w + a3.w + b4.w, 0.0f);
    ushort4 hv, lv;
    hv.x = f2b(ox); lv.x = f2b(ox - b2f(hv.x));
    hv.y = f2b(oy); lv.y = f2b(oy - b2f(hv.y));
    hv.z = f2b(oz); lv.z = f2b(oz - b2f(hv.z));
    hv.w = f2b(ow); lv.w = f2b(ow - b2f(hv.w));
    *reinterpret_cast<ushort4*>(&g_hi[(size_t)node * HID + cb]) = hv;
    *reinterpret_cast<ushort4*>(&g_lo[(size_t)node * HID + cb]) = lv;
}

// ---------------- fused sequential GRU ----------------

// Per 32-row block: gi = G_t@W_ih and gh = h@W_hh via bf16x3 MFMA (K=128 in LDS),
// gates in epilogue, writes h fp32 + h_hi/h_lo. 4 waves; wave w owns HID cols
// [32w,32w+32) across all 3 gates of BOTH GEMMs -> gate math thread-local.
// acc = 2 mat x 3 gate x 2 mfrag x 2 nfrag x f32x4 = 96 VGPR. 288 MFMA/wave.
__global__ __launch_bounds__(256)
void gru_fused2(const u16* __restrict__ g_hi, const u16* __restrict__ g_lo,
                const u16* __restrict__ h_hi, const u16* __restrict__ h_lo,
                const u16* __restrict__ WihT_hi, const u16* __restrict__ WihT_lo,
                const u16* __restrict__ WhhT_hi, const u16* __restrict__ WhhT_lo,
                const float* __restrict__ b_ih, const float* __restrict__ b_hh,
                float* __restrict__ h, u16* __restrict__ h_hi_o, u16* __restrict__ h_lo_o,
                int n) {
    __shared__ u16 lds[4][32 * 128];   // [ghi|glo|hhi|hlo], XOR-swizzled; 32 KB
    const int tid  = threadIdx.x;
    const int row0 = blockIdx.x * 32;

    #pragma unroll
    for (int it = 0; it < 2; ++it) {
        int unit = tid + it * 256;          // 0..511
        int r = unit >> 4, s = unit & 15;
        int gr = row0 + r;
        uint4 vg = make_uint4(0,0,0,0), vG = vg, vh = vg, vH = vg;
        if (gr < n) {
            size_t goff = (size_t)gr * 128 + s * 8;
            vg = *reinterpret_cast<const uint4*>(&g_hi[goff]);
            vG = *reinterpret_cast<const uint4*>(&g_lo[goff]);
            vh = *reinterpret_cast<const uint4*>(&h_hi[goff]);
            vH = *reinterpret_cast<const uint4*>(&h_lo[goff]);
        }
        int byte = (r * 256 + s * 16) ^ ((r & 7) << 4);
        *reinterpret_cast<uint4*>((char*)(&lds[0][0]) + byte) = vg;
        *reinterpret_cast<uint4*>((char*)(&lds[1][0]) + byte) = vG;
        *reinterpret_cast<uint4*>((char*)(&lds[2][0]) + byte) = vh;
        *reinterpret_cast<uint4*>((char*)(&lds[3][0]) + byte) = vH;
    }
    __syncthreads();

    const int wid  = tid >> 6;
    const int lane = tid & 63;
    const int l15  = lane & 15;
    const int lkh  = lane >> 4;

    f32x4_t agi[3][2][2] = {};   // [gate][m][nf]
    f32x4_t agh[3][2][2] = {};

    #pragma unroll
    for (int kb = 0; kb < 4; ++kb) {
        bf16x8_t Agh[2], Agl[2], Ahh[2], Ahl[2];
        #pragma unroll
        for (int m = 0; m < 2; ++m) {
            int row = m * 16 + l15;
            int byte = (row * 256 + kb * 64 + lkh * 16) ^ ((row & 7) << 4);
            Agh[m] = *reinterpret_cast<const bf16x8_t*>((const char*)(&lds[0][0]) + byte);
            Agl[m] = *reinterpret_cast<const bf16x8_t*>((const char*)(&lds[1][0]) + byte);
            Ahh[m] = *reinterpret_cast<const bf16x8_t*>((const char*)(&lds[2][0]) + byte);
            Ahl[m] = *reinterpret_cast<const bf16x8_t*>((const char*)(&lds[3][0]) + byte);
        }
        #pragma unroll
        for (int gt = 0; gt < 3; ++gt) {
            #pragma unroll
            for (int nf = 0; nf < 2; ++nf) {
                int col = gt * HID + wid * 32 + nf * 16 + l15;
                size_t off = (size_t)col * 128 + kb * 32 + lkh * 8;
                bf16x8_t bih = *reinterpret_cast<const bf16x8_t*>(&WihT_hi[off]);
                bf16x8_t bil = *reinterpret_cast<const bf16x8_t*>(&WihT_lo[off]);
                bf16x8_t bhh = *reinterpret_cast<const bf16x8_t*>(&WhhT_hi[off]);
                bf16x8_t bhl = *reinterpret_cast<const bf16x8_t*>(&WhhT_lo[off]);
                #pragma unroll
                for (int m = 0; m < 2; ++m) {
                    agi[gt][m][nf] = __builtin_amdgcn_mfma_f32_16x16x32_bf16(Agh[m], bih, agi[gt][m][nf], 0, 0, 0);
                    agi[gt][m][nf] = __builtin_amdgcn_mfma_f32_16x16x32_bf16(Agh[m], bil, agi[gt][m][nf], 0, 0, 0);
                    agi[gt][m][nf] = __builtin_amdgcn_mfma_f32_16x16x32_bf16(Agl[m], bih, agi[gt][m][nf], 0, 0, 0);
                    agh[gt][m][nf] = __builtin_amdgcn_mfma_f32_16x16x32_bf16(Ahh[m], bhh, agh[gt][m][nf], 0, 0, 0);
                    agh[gt][m][nf] = __builtin_amdgcn_mfma_f32_16x16x32_bf16(Ahh[m], bhl, agh[gt][m][nf], 0, 0, 0);
                    agh[gt][m][nf] = __builtin_amdgcn_mfma_f32_16x16x32_bf16(Ahl[m], bhh, agh[gt][m][nf], 0, 0, 0);
                }
            }
        }
    }

    // epilogue: gates. C layout col=l15-based, row=lkh*4+r2 (+16m)
    #pragma unroll
    for (int nf = 0; nf < 2; ++nf) {
        int col = wid * 32 + nf * 16 + l15;
        float bir = b_ih[col], biz = b_ih[HID + col], bin_ = b_ih[2 * HID + col];
        float bhr = b_hh[col], bhz = b_hh[HID + col], bhn = b_hh[2 * HID + col];
        #pragma unroll
        for (int m = 0; m < 2; ++m) {
            #pragma unroll
            for (int r2 = 0; r2 < 4; ++r2) {
                int grow = row0 + m * 16 + lkh * 4 + r2;
                if (grow >= n) continue;
                float rr = sigmoidf_((agi[0][m][nf][r2] + bir) + (agh[0][m][nf][r2] + bhr));
                float zz = sigmoidf_((agi[1][m][nf][r2] + biz) + (agh[1][m][nf][r2] + bhz));
                float nn2 = tanhf((agi[2][m][nf][r2] + bin_) + rr * (agh[2][m][nf][r2] + bhn));
                size_t off = (size_t)grow * HID + col;
                float hold = h[off];
                float hnew = (1.0f - zz) * nn2 + zz * hold;
                h[off] = hnew;
                u16 hv = f2b(hnew);
                h_hi_o[off] = hv;
                h_lo_o[off] = f2b(hnew - b2f(hv));
            }
        }
    }
}

// ---------------- launcher ----------------

extern "C" void kernel_launch(void* const* d_in, const int* in_sizes, int n_in,
                              void* d_out, int out_size, void* d_ws, size_t ws_size,
                              hipStream_t stream) {
    const float* x        = (const float*)d_in[0];
    const float* edge_attr= (const float*)d_in[1];
    const float* W_lin    = (const float*)d_in[2];
    const float* b_lin    = (const float*)d_in[3];
    const float* Wc1      = (const float*)d_in[4];
    const float* bc1      = (const float*)d_in[5];
    const float* Wc2      = (const float*)d_in[6];
    const float* bc2      = (const float*)d_in[7];
    const float* W_ih     = (const float*)d_in[8];
    const float* b_ih     = (const float*)d_in[9];
    const float* W_hh     = (const float*)d_in[10];
    const float* b_hh     = (const float*)d_in[11];
    const float* Wf1      = (const float*)d_in[12];
    const float* bf1      = (const float*)d_in[13];
    const float* Wf2      = (const float*)d_in[14];
    const float* bf2      = (const float*)d_in[15];
    const float* Wg1      = (const float*)d_in[16];
    const float* bg1      = (const float*)d_in[17];
    const float* Wg2      = (const float*)d_in[18];
    const float* bg2      = (const float*)d_in[19];
    const int*   edge_index = (const int*)d_in[20];
    const int*   mask     = (const int*)d_in[21];

    const int n = in_sizes[21];       // 20000
    const int e = in_sizes[1];        // 320000
    const int* src = edge_index;
    const int* dst = edge_index + e;
    float* h = (float*)d_out;         // [n,128], GRU state (fp32)

    char* w = (char*)d_ws;
    auto alloc = [&](size_t bytes) -> char* {
        char* p = w;
        w += (bytes + 255) & ~(size_t)255;
        return p;
    };
    int*   first_eid = (int*)  alloc((size_t)n * 4);
    int*   deg_cnt   = (int*)  alloc((size_t)n * 4);
    int*   row_ptr   = (int*)  alloc((size_t)(n + 1) * 4);
    int*   fill_ptr  = (int*)  alloc((size_t)n * 4);
    int*   tmp_scan  = (int*)  alloc((size_t)n * 4);
    int*   bsum      = (int*)  alloc((size_t)256 * 4);
    float* dis       = (float*)alloc((size_t)n * 4);
    float* norm_self = (float*)alloc((size_t)n * 4);
    int*   first_out = (int*)  alloc((size_t)n * 4);
    float* first_dx  = (float*)alloc((size_t)n * 4);
    int*   d1_of     = (int*)  alloc((size_t)n * 4);
    int*   d2_of     = (int*)  alloc((size_t)n * 4);
    float* dxb_of    = (float*)alloc((size_t)n * 4);
    int*   ghost_list= (int*)  alloc((size_t)n * 4);
    int*   ghost_pos = (int*)  alloc((size_t)n * 4);
    int*   gcount    = (int*)  alloc(256);
    int*   csr_src   = (int*)  alloc((size_t)e * 4);
    float* csr_w     = (float*)alloc((size_t)e * 4);
    // bf16 split weight transposes BT[n][k]
    u16* Wc1T_hi = (u16*)alloc((size_t)HID * 128 * 2);
    u16* Wc1T_lo = (u16*)alloc((size_t)HID * 128 * 2);
    u16* Wc2T_hi = (u16*)alloc((size_t)HID * 128 * 2);
    u16* Wc2T_lo = (u16*)alloc((size_t)HID * 128 * 2);
    u16* WihT_hi = (u16*)alloc((size_t)H3 * 128 * 2);
    u16* WihT_lo = (u16*)alloc((size_t)H3 * 128 * 2);
    u16* WhhT_hi = (u16*)alloc((size_t)H3 * 128 * 2);
    u16* WhhT_lo = (u16*)alloc((size_t)H3 * 128 * 2);
    // activations (batched over all T_IN)
    u16*   g8_hi = (u16*)  alloc((size_t)T_IN * n * HID * 2);   // 41 MB
    u16*   g8_lo = (u16*)  alloc((size_t)T_IN * n * HID * 2);   // 41 MB
    u16*   bufHb = (u16*)  alloc((size_t)T_IN * n * HID * 2);   // 41 MB
    float* xf_buf= (float*)alloc((size_t)n * T_IN * FEAT * 4);  // 41 MB
    u16*   h_hi  = (u16*)  alloc((size_t)n * HID * 2);          // adjacent to h_lo
    u16*   h_lo  = (u16*)  alloc((size_t)n * HID * 2);

    const int TPB = 256;
    const int nb = (n + 255) / 256;
    dim3 gN(nb), gE((e + TPB - 1) / TPB);

    // preprocessing (time-invariant)
    init_kernel<<<gN, TPB, 0, stream>>>(first_eid, deg_cnt, gcount, n);
    edge_pass1<<<gE, TPB, 0, stream>>>(src, dst, first_eid, deg_cnt, e);
    scan1<<<gN, TPB, 0, stream>>>(deg_cnt, tmp_scan, bsum, n);
    scan2<<<1, TPB, 0, stream>>>(bsum, nb);
    scan3<<<gN, TPB, 0, stream>>>(deg_cnt, tmp_scan, bsum, row_ptr, fill_ptr, dis, norm_self, n);
    firsts_kernel<<<gN, TPB, 0, stream>>>(first_eid, dst, edge_attr, first_out, first_dx, n, e);
    edge_pass2<<<gE, TPB, 0, stream>>>(src, dst, fill_ptr, dis, csr_src, csr_w, e);
    ghost_kernel<<<gN, TPB, 0, stream>>>(mask, first_out, first_dx, d1_of, d2_of, dxb_of,
                                         ghost_list, ghost_pos, gcount, n);
    wsplit_kernel<<<dim3(HID / 32, 4), TPB, 0, stream>>>(Wc1, Wc1T_hi, Wc1T_lo, HID);
    wsplit_kernel<<<dim3(HID / 32, 4), TPB, 0, stream>>>(Wc2, Wc2T_hi, Wc2T_lo, HID);
    wsplit_kernel<<<dim3(H3 / 32, 4), TPB, 0, stream>>>(W_ih, WihT_hi, WihT_lo, H3);
    wsplit_kernel<<<dim3(H3 / 32, 4), TPB, 0, stream>>>(W_hh, WhhT_hi, WhhT_lo, H3);

    // h0 = 0 (fp32) and split hi/lo (adjacent region, as u32 words)
    zero2_kernel<<<2048, TPB, 0, stream>>>(h, n * HID, (unsigned*)h_hi, n * HID);

    // ---- Phase A: front end for ALL timesteps (independent of h) ----
    fuse_ghost<<<dim3(n, T_IN), 128, 0, stream>>>(x, ghost_list, gcount, d1_of, d2_of, dxb_of,
                                                  Wf1, bf1, Wf2, bf2, Wg1, bg1, Wg2, bg2,
                                                  xf_buf);
    lin_all<<<2048, 256, 0, stream>>>(x, xf_buf, ghost_pos, W_lin, b_lin,
                                      g8_hi, g8_lo, n, n * T_IN);
    dim3 grid_gcn((n + 63) / 64, 1, T_IN);
    const int nblk16 = (n + 15) / 16;
    const int agg_blocks = 2 * 8 * nblk16;      // half-major, t in low bits
    gemm_gcn_b<<<grid_gcn, 256, 0, stream>>>(g8_hi, g8_lo, Wc1T_hi, Wc1T_lo, bufHb, n);
    gcn_agg_b<<<agg_blocks, 256, 0, stream>>>(bufHb, row_ptr, csr_src, csr_w,
                                              norm_self, bc1, g8_hi, g8_lo, n, nblk16);
    gemm_gcn_b<<<grid_gcn, 256, 0, stream>>>(g8_hi, g8_lo, Wc2T_hi, Wc2T_lo, bufHb, n);
    gcn_agg_b<<<agg_blocks, 256, 0, stream>>>(bufHb, row_ptr, csr_src, csr_w,
                                              norm_self, bc2, g8_hi, g8_lo, n, nblk16);

    // ---- Phase B: fused sequential GRU over timesteps ----
    const int gru_blocks = (n + 31) / 32;
    for (int t = 0; t < T_IN; ++t) {
        const u16* Gt_hi = g8_hi + (size_t)t * n * HID;
        const u16* Gt_lo = g8_lo + (size_t)t * n * HID;
        gru_fused2<<<gru_blocks, 256, 0, stream>>>(Gt_hi, Gt_lo, h_hi, h_lo,
                                                   WihT_hi, WihT_lo, WhhT_hi, WhhT_lo,
                                                   b_ih, b_hh, h, h_hi, h_lo, n);
    }
}

// Round 13
// 934.621 us; speedup vs baseline: 1.0194x; 1.0194x over previous
//
#include <hip/hip_runtime.h>
#include <math.h>

// Problem constants (match reference)
#define NN 20000
#define T_IN 8
#define FEAT 16
#define HID 128
#define H3 384
#define FUSER_IN 49
#define FUSER_H 96
#define GATE_H 48
#define ALPHA 0.5f

typedef unsigned short u16;
typedef __attribute__((ext_vector_type(8))) short bf16x8_t;
typedef __attribute__((ext_vector_type(4))) float f32x4_t;

__device__ __forceinline__ float sigmoidf_(float v) { return 1.0f / (1.0f + expf(-v)); }

// bf16 round-to-nearest-even (finite values only)
__device__ __forceinline__ u16 f2b(float v) {
    unsigned u = __float_as_uint(v);
    unsigned r = (u + 0x7fffu + ((u >> 16) & 1u)) >> 16;
    return (u16)r;
}
__device__ __forceinline__ float b2f(u16 u) { return __uint_as_float(((unsigned)u) << 16); }

// ---------------- preprocessing ----------------

__global__ void init_kernel(int* first_eid, int* deg_cnt, int* gcount, int n) {
    int i = blockIdx.x * 256 + threadIdx.x;
    if (i < n) { first_eid[i] = 0x7fffffff; deg_cnt[i] = 0; }
    if (i == 0) *gcount = 0;
}

__global__ void edge_pass1(const int* __restrict__ src, const int* __restrict__ dst,
                           int* first_eid, int* deg_cnt, int e) {
    int i = blockIdx.x * 256 + threadIdx.x;
    if (i < e) {
        atomicMin(&first_eid[src[i]], i);
        atomicAdd(&deg_cnt[dst[i]], 1);
    }
}

// 3-phase parallel prefix sum over cnt[n] (n <= 256*256)
__global__ void scan1(const int* __restrict__ cnt, int* tmp, int* bsum, int n) {
    __shared__ int buf[256];
    int tid = threadIdx.x;
    int i = blockIdx.x * 256 + tid;
    int v = (i < n) ? cnt[i] : 0;
    buf[tid] = v;
    __syncthreads();
    #pragma unroll
    for (int off = 1; off < 256; off <<= 1) {
        int t = (tid >= off) ? buf[tid - off] : 0;
        __syncthreads();
        buf[tid] += t;
        __syncthreads();
    }
    if (i < n) tmp[i] = buf[tid];
    if (tid == 255) bsum[blockIdx.x] = buf[255];
}

__global__ void scan2(int* bsum, int nb) {
    __shared__ int buf[256];
    int tid = threadIdx.x;
    int v = (tid < nb) ? bsum[tid] : 0;
    buf[tid] = v;
    __syncthreads();
    #pragma unroll
    for (int off = 1; off < 256; off <<= 1) {
        int t = (tid >= off) ? buf[tid - off] : 0;
        __syncthreads();
        buf[tid] += t;
        __syncthreads();
    }
    if (tid < nb) bsum[tid] = buf[tid];   // inclusive block sums
}

__global__ void scan3(const int* __restrict__ cnt, const int* __restrict__ tmp,
                      const int* __restrict__ bsum,
                      int* row_ptr, int* fill_ptr, float* dis, float* norm_self, int n) {
    int i = blockIdx.x * 256 + threadIdx.x;
    if (i >= n) return;
    int pre = (blockIdx.x > 0) ? bsum[blockIdx.x - 1] : 0;
    int incl = tmp[i] + pre;
    int v = cnt[i];
    row_ptr[i + 1] = incl;
    fill_ptr[i] = incl - v;
    float deg = (float)v + 1.0f;
    dis[i] = 1.0f / sqrtf(deg);
    norm_self[i] = 1.0f / deg;
    if (i == 0) row_ptr[0] = 0;
}

__global__ void firsts_kernel(const int* __restrict__ first_eid, const int* __restrict__ dst,
                              const float* __restrict__ edge_attr,
                              int* first_out, float* first_dx, int n, int e) {
    int i = blockIdx.x * 256 + threadIdx.x;
    if (i >= n) return;
    int fe = first_eid[i];
    if (fe < e) {
        first_out[i] = dst[fe];
        first_dx[i] = fmaxf(edge_attr[fe], 1e-6f);
    } else {
        first_out[i] = -1;
        first_dx[i] = -1.0f;
    }
}

__global__ void edge_pass2(const int* __restrict__ src, const int* __restrict__ dst,
                           int* fill_ptr, const float* __restrict__ dis,
                           int* csr_src, float* csr_w, int e) {
    int i = blockIdx.x * 256 + threadIdx.x;
    if (i < e) {
        int d = dst[i], s = src[i];
        int pos = atomicAdd(&fill_ptr[d], 1);
        csr_src[pos] = s;
        csr_w[pos] = dis[s] * dis[d];
    }
}

// ghost prep + compaction: ghost_pos[node] = slot or -1; ghost_list[slot] = node
__global__ void ghost_kernel(const int* __restrict__ mask, const int* __restrict__ first_out,
                             const float* __restrict__ first_dx,
                             int* d1_of, int* d2_of, float* dxb_of,
                             int* ghost_list, int* ghost_pos, int* gcount, int n) {
    int i = blockIdx.x * 256 + threadIdx.x;
    if (i >= n) return;
    if (mask[i] != 0) { ghost_pos[i] = -1; return; }
    int pos = atomicAdd(gcount, 1);
    ghost_list[pos] = i;
    ghost_pos[i] = pos;
    int b = first_out[i];
    float dxb = fmaxf(first_dx[i], 1e-6f);
    int d1, d2;
    if (b < 0) { d1 = i; d2 = i; }
    else {
        int n1 = first_out[b]; d1 = (n1 < 0) ? b : n1;
        int n2 = first_out[d1]; d2 = (n2 < 0) ? d1 : n2;
    }
    d1_of[i] = d1; d2_of[i] = d2; dxb_of[i] = dxb;
}

// zero two regions in one dispatch (grid-stride)
__global__ void zero2_kernel(float* a, int na, unsigned* b, int nb) {
    int stride = gridDim.x * 256;
    for (int i = blockIdx.x * 256 + threadIdx.x; i < na; i += stride) a[i] = 0.0f;
    for (int i = blockIdx.x * 256 + threadIdx.x; i < nb; i += stride) b[i] = 0u;
}

// W[k][nn] (K=128) -> BT_hi/BT_lo[nn][k] bf16 split, LDS-tiled transpose (coalesced both sides)
__global__ __launch_bounds__(256)
void wsplit_kernel(const float* __restrict__ W, u16* BT_hi, u16* BT_lo, int Ncols) {
    __shared__ float tile[32][33];
    int nb = blockIdx.x * 32;           // column-of-W (=row-of-BT) base
    int kb = blockIdx.y * 32;           // k base
    int tx = threadIdx.x & 31, ty = threadIdx.x >> 5;   // 32 x 8
    #pragma unroll
    for (int r = 0; r < 32; r += 8)
        tile[ty + r][tx] = W[(size_t)(kb + ty + r) * Ncols + nb + tx];
    __syncthreads();
    #pragma unroll
    for (int r = 0; r < 32; r += 8) {
        float v = tile[tx][ty + r];     // = W[kb+tx][nb+ty+r]
        u16 h = f2b(v);
        size_t off = (size_t)(nb + ty + r) * 128 + kb + tx;
        BT_hi[off] = h;
        BT_lo[off] = f2b(v - b2f(h));
    }
}

// ---------------- batched front-end kernels ----------------

// Ghost fusion only: blockIdx.x = ghost slot (exit if >= gcount), blockIdx.y = t.
__global__ __launch_bounds__(128)
void fuse_ghost(const float* __restrict__ x,
                const int* __restrict__ ghost_list, const int* __restrict__ gcount,
                const int* __restrict__ d1_of, const int* __restrict__ d2_of,
                const float* __restrict__ dxb_of,
                const float* __restrict__ Wf1, const float* __restrict__ bf1,
                const float* __restrict__ Wf2, const float* __restrict__ bf2,
                const float* __restrict__ Wg1, const float* __restrict__ bg1,
                const float* __restrict__ Wg2, const float* __restrict__ bg2,
                float* __restrict__ xf_buf) {
    int slot = blockIdx.x;
    if (slot >= *gcount) return;
    int t = blockIdx.y;
    int i = ghost_list[slot];
    int j = threadIdx.x;
    __shared__ float feats[FUSER_IN];
    __shared__ float z1[FUSER_H];
    __shared__ float zg[GATE_H];
    __shared__ float s_gate;

    if (j < FEAT) {
        int d1 = d1_of[i], d2 = d2_of[i];
        feats[j]            = x[((size_t)i * T_IN + t) * FEAT + j];
        feats[FEAT + j]     = x[((size_t)d1 * T_IN + t) * FEAT + j];
        feats[2 * FEAT + j] = x[((size_t)d2 * T_IN + t) * FEAT + j];
    }
    if (j == 0) feats[3 * FEAT] = dxb_of[i];
    __syncthreads();
    if (j < FUSER_H) {
        float acc = bf1[j];
        for (int k = 0; k < FUSER_IN; ++k) acc = fmaf(feats[k], Wf1[k * FUSER_H + j], acc);
        z1[j] = fmaxf(acc, 0.0f);
    }
    if (j < GATE_H) {
        float acc = bg1[j];
        for (int k = 0; k < FUSER_IN; ++k) acc = fmaf(feats[k], Wg1[k * GATE_H + j], acc);
        zg[j] = fmaxf(acc, 0.0f);
    }
    __syncthreads();
    if (j == 0) {
        float s = bg2[0];
        for (int k = 0; k < GATE_H; ++k) s = fmaf(zg[k], Wg2[k], s);
        s_gate = sigmoidf_(s);
    }
    __syncthreads();
    if (j < FEAT) {
        float acc = bf2[j];
        for (int k = 0; k < FUSER_H; ++k) acc = fmaf(z1[k], Wf2[k * FEAT + j], acc);
        xf_buf[((size_t)slot * T_IN + t) * FEAT + j] = feats[j] + ALPHA * acc * s_gate;
    }
}

// g = relu(xf @ W_lin + b_lin) for ALL (t,node) pairs. Grid-stride, 2 pairs/block,
// W_lin+b_lin cached in LDS. Output g8[t][node][128] bf16 hi/lo.
__global__ __launch_bounds__(256)
void lin_all(const float* __restrict__ x, const float* __restrict__ xf_buf,
             const int* __restrict__ ghost_pos,
             const float* __restrict__ W_lin, const float* __restrict__ b_lin,
             u16* __restrict__ g8_hi, u16* __restrict__ g8_lo, int n, int total) {
    __shared__ float Wl[FEAT][HID];
    __shared__ float bl[HID];
    #pragma unroll
    for (int k8 = 0; k8 < 8; ++k8) {
        int idx = threadIdx.x + k8 * 256;
        Wl[idx >> 7][idx & 127] = W_lin[idx];
    }
    if (threadIdx.x < HID) bl[threadIdx.x] = b_lin[threadIdx.x];
    __syncthreads();
    int j = threadIdx.x & 127;
    for (int pair = blockIdx.x * 2 + (threadIdx.x >> 7); pair < total; pair += gridDim.x * 2) {
        int node = pair % n;
        int t = pair / n;
        int gp = ghost_pos[node];
        const float* xr = (gp >= 0) ? &xf_buf[((size_t)gp * T_IN + t) * FEAT]
                                    : &x[((size_t)node * T_IN + t) * FEAT];
        float acc = bl[j];
        #pragma unroll
        for (int k = 0; k < FEAT; ++k) acc = fmaf(xr[k], Wl[k][j], acc);
        float v = fmaxf(acc, 0.0f);
        u16 hv = f2b(v);
        size_t off = (size_t)pair * HID + j;
        g8_hi[off] = hv;
        g8_lo[off] = f2b(v - b2f(hv));
    }
}

// Batched GCN GEMM: Cb[t][M x 128] = bf16(A[t] @ B), bf16x3 MFMA. BM=64, blockIdx.z = t.
__global__ __launch_bounds__(256)
void gemm_gcn_b(const u16* __restrict__ Ahi0, const u16* __restrict__ Alo0,
                const u16* __restrict__ BThi, const u16* __restrict__ BTlo,
                u16* __restrict__ Cb0, int M) {
    constexpr int BM = 64;
    __shared__ u16 ldsA[2][BM * 128];
    const size_t tOff = (size_t)blockIdx.z * M * 128;
    const u16* Ahi = Ahi0 + tOff;
    const u16* Alo = Alo0 + tOff;
    u16*       Cb  = Cb0 + tOff;

    const int tid  = threadIdx.x;
    const int row0 = blockIdx.x * BM;
    constexpr int MF = BM / 32;

    #pragma unroll
    for (int it = 0; it < BM / 16; ++it) {
        int unit = tid + it * 256;
        int r = unit >> 4, s = unit & 15;
        int gr = row0 + r;
        uint4 vh = make_uint4(0, 0, 0, 0), vl = vh;
        if (gr < M) {
            vh = *reinterpret_cast<const uint4*>(&Ahi[(size_t)gr * 128 + s * 8]);
            vl = *reinterpret_cast<const uint4*>(&Alo[(size_t)gr * 128 + s * 8]);
        }
        int byte = (r * 256 + s * 16) ^ ((r & 7) << 4);
        *reinterpret_cast<uint4*>((char*)(&ldsA[0][0]) + byte) = vh;
        *reinterpret_cast<uint4*>((char*)(&ldsA[1][0]) + byte) = vl;
    }
    __syncthreads();

    const int wid  = tid >> 6;
    const int lane = tid & 63;
    const int wr = (wid >> 1) * (BM / 2);
    const int wc = (wid & 1) * 64;
    const int l15 = lane & 15;
    const int lkh = lane >> 4;

    f32x4_t acc[MF][4] = {};

    #pragma unroll
    for (int kb = 0; kb < 4; ++kb) {
        bf16x8_t ah[MF], al[MF], bh[4], bl[4];
        #pragma unroll
        for (int m = 0; m < MF; ++m) {
            int row = wr + m * 16 + l15;
            int byte = (row * 256 + kb * 64 + lkh * 16) ^ ((row & 7) << 4);
            ah[m] = *reinterpret_cast<const bf16x8_t*>((const char*)(&ldsA[0][0]) + byte);
            al[m] = *reinterpret_cast<const bf16x8_t*>((const char*)(&ldsA[1][0]) + byte);
        }
        #pragma unroll
        for (int nf = 0; nf < 4; ++nf) {
            int col = wc + nf * 16 + l15;
            size_t off = (size_t)col * 128 + kb * 32 + lkh * 8;
            bh[nf] = *reinterpret_cast<const bf16x8_t*>(&BThi[off]);
            bl[nf] = *reinterpret_cast<const bf16x8_t*>(&BTlo[off]);
        }
        #pragma unroll
        for (int m = 0; m < MF; ++m)
            #pragma unroll
            for (int nf = 0; nf < 4; ++nf) {
                acc[m][nf] = __builtin_amdgcn_mfma_f32_16x16x32_bf16(ah[m], bh[nf], acc[m][nf], 0, 0, 0);
                acc[m][nf] = __builtin_amdgcn_mfma_f32_16x16x32_bf16(ah[m], bl[nf], acc[m][nf], 0, 0, 0);
                acc[m][nf] = __builtin_amdgcn_mfma_f32_16x16x32_bf16(al[m], bh[nf], acc[m][nf], 0, 0, 0);
            }
    }

    #pragma unroll
    for (int m = 0; m < MF; ++m) {
        int rbase = row0 + wr + m * 16 + lkh * 4;
        #pragma unroll
        for (int nf = 0; nf < 4; ++nf) {
            int col = wc + nf * 16 + l15;
            #pragma unroll
            for (int r2 = 0; r2 < 4; ++r2) {
                int row = rbase + r2;
                if (row < M) Cb[(size_t)row * 128 + col] = f2b(acc[m][nf][r2]);
            }
        }
    }
}

// Batched gi GEMM: gi8[t][M x 384] (fp32) = G[t] @ W_ih, bf16x3 MFMA.
// BM=64, grid (ceil(M/64), 3, 8): blockIdx.y = 128-col tile, blockIdx.z = t.
__global__ __launch_bounds__(256)
void gemm_gi_b(const u16* __restrict__ Ahi0, const u16* __restrict__ Alo0,
               const u16* __restrict__ BThi, const u16* __restrict__ BTlo,
               float* __restrict__ C0, int M) {
    constexpr int BM = 64;
    __shared__ u16 ldsA[2][BM * 128];
    const u16* Ahi = Ahi0 + (size_t)blockIdx.z * M * 128;
    const u16* Alo = Alo0 + (size_t)blockIdx.z * M * 128;
    float*     C   = C0 + (size_t)blockIdx.z * M * H3;
    const int col0 = blockIdx.y * 128;

    const int tid  = threadIdx.x;
    const int row0 = blockIdx.x * BM;
    constexpr int MF = BM / 32;

    #pragma unroll
    for (int it = 0; it < BM / 16; ++it) {
        int unit = tid + it * 256;
        int r = unit >> 4, s = unit & 15;
        int gr = row0 + r;
        uint4 vh = make_uint4(0, 0, 0, 0), vl = vh;
        if (gr < M) {
            vh = *reinterpret_cast<const uint4*>(&Ahi[(size_t)gr * 128 + s * 8]);
            vl = *reinterpret_cast<const uint4*>(&Alo[(size_t)gr * 128 + s * 8]);
        }
        int byte = (r * 256 + s * 16) ^ ((r & 7) << 4);
        *reinterpret_cast<uint4*>((char*)(&ldsA[0][0]) + byte) = vh;
        *reinterpret_cast<uint4*>((char*)(&ldsA[1][0]) + byte) = vl;
    }
    __syncthreads();

    const int wid  = tid >> 6;
    const int lane = tid & 63;
    const int wr = (wid >> 1) * (BM / 2);
    const int wc = (wid & 1) * 64;
    const int l15 = lane & 15;
    const int lkh = lane >> 4;

    f32x4_t acc[MF][4] = {};

    #pragma unroll
    for (int kb = 0; kb < 4; ++kb) {
        bf16x8_t ah[MF], al[MF], bh[4], bl[4];
        #pragma unroll
        for (int m = 0; m < MF; ++m) {
            int row = wr + m * 16 + l15;
            int byte = (row * 256 + kb * 64 + lkh * 16) ^ ((row & 7) << 4);
            ah[m] = *reinterpret_cast<const bf16x8_t*>((const char*)(&ldsA[0][0]) + byte);
            al[m] = *reinterpret_cast<const bf16x8_t*>((const char*)(&ldsA[1][0]) + byte);
        }
        #pragma unroll
        for (int nf = 0; nf < 4; ++nf) {
            int col = col0 + wc + nf * 16 + l15;
            size_t off = (size_t)col * 128 + kb * 32 + lkh * 8;
            bh[nf] = *reinterpret_cast<const bf16x8_t*>(&BThi[off]);
            bl[nf] = *reinterpret_cast<const bf16x8_t*>(&BTlo[off]);
        }
        #pragma unroll
        for (int m = 0; m < MF; ++m)
            #pragma unroll
            for (int nf = 0; nf < 4; ++nf) {
                acc[m][nf] = __builtin_amdgcn_mfma_f32_16x16x32_bf16(ah[m], bh[nf], acc[m][nf], 0, 0, 0);
                acc[m][nf] = __builtin_amdgcn_mfma_f32_16x16x32_bf16(ah[m], bl[nf], acc[m][nf], 0, 0, 0);
                acc[m][nf] = __builtin_amdgcn_mfma_f32_16x16x32_bf16(al[m], bh[nf], acc[m][nf], 0, 0, 0);
            }
    }

    #pragma unroll
    for (int m = 0; m < MF; ++m) {
        int rbase = row0 + wr + m * 16 + lkh * 4;
        #pragma unroll
        for (int nf = 0; nf < 4; ++nf) {
            int col = col0 + wc + nf * 16 + l15;
            #pragma unroll
            for (int r2 = 0; r2 < 4; ++r2) {
                int row = rbase + r2;
                if (row < M) C[(size_t)row * H3 + col] = acc[m][nf][r2];
            }
        }
    }
}

// Batched GCN aggregate (R7 proven shape): full 128 cols, 8 nodes/block,
// 32 lanes/node, 1D grid with t = blockIdx.x & 7 (XCD affinity).
__global__ __launch_bounds__(256)
void gcn_agg_b(const u16* __restrict__ hwb0,
               const int* __restrict__ row_ptr,
               const int* __restrict__ csr_src, const float* __restrict__ csr_w,
               const float* __restrict__ norm_self, const float* __restrict__ bias,
               u16* __restrict__ g_hi0, u16* __restrict__ g_lo0, int n) {
    int t   = blockIdx.x & 7;
    int blk = blockIdx.x >> 3;
    int node = blk * 8 + (threadIdx.x >> 5);
    int lane = threadIdx.x & 31;
    if (node >= n) return;
    const size_t tOff = (size_t)t * n * 128;
    const u16* hwb = hwb0 + tOff;
    u16* g_hi = g_hi0 + tOff;
    u16* g_lo = g_lo0 + tOff;

    ushort4 sv = *reinterpret_cast<const ushort4*>(&hwb[(size_t)node * HID + lane * 4]);
    float ns = norm_self[node];
    float4 a0, a1, a2, a3;
    a0.x = b2f(sv.x) * ns; a0.y = b2f(sv.y) * ns; a0.z = b2f(sv.z) * ns; a0.w = b2f(sv.w) * ns;
    a1 = make_float4(0.f, 0.f, 0.f, 0.f); a2 = a1; a3 = a1;
    int p  = row_ptr[node];
    int p1 = row_ptr[node + 1];
    for (; p + 4 <= p1; p += 4) {
        int s0 = csr_src[p], s1 = csr_src[p + 1], s2 = csr_src[p + 2], s3 = csr_src[p + 3];
        float w0 = csr_w[p], w1 = csr_w[p + 1], w2 = csr_w[p + 2], w3 = csr_w[p + 3];
        ushort4 v0 = *reinterpret_cast<const ushort4*>(&hwb[(size_t)s0 * HID + lane * 4]);
        ushort4 v1 = *reinterpret_cast<const ushort4*>(&hwb[(size_t)s1 * HID + lane * 4]);
        ushort4 v2 = *reinterpret_cast<const ushort4*>(&hwb[(size_t)s2 * HID + lane * 4]);
        ushort4 v3 = *reinterpret_cast<const ushort4*>(&hwb[(size_t)s3 * HID + lane * 4]);
        a0.x = fmaf(b2f(v0.x), w0, a0.x); a0.y = fmaf(b2f(v0.y), w0, a0.y);
        a0.z = fmaf(b2f(v0.z), w0, a0.z); a0.w = fmaf(b2f(v0.w), w0, a0.w);
        a1.x = fmaf(b2f(v1.x), w1, a1.x); a1.y = fmaf(b2f(v1.y), w1, a1.y);
        a1.z = fmaf(b2f(v1.z), w1, a1.z); a1.w = fmaf(b2f(v1.w), w1, a1.w);
        a2.x = fmaf(b2f(v2.x), w2, a2.x); a2.y = fmaf(b2f(v2.y), w2, a2.y);
        a2.z = fmaf(b2f(v2.z), w2, a2.z); a2.w = fmaf(b2f(v2.w), w2, a2.w);
        a3.x = fmaf(b2f(v3.x), w3, a3.x); a3.y = fmaf(b2f(v3.y), w3, a3.y);
        a3.z = fmaf(b2f(v3.z), w3, a3.z); a3.w = fmaf(b2f(v3.w), w3, a3.w);
    }
    for (; p < p1; ++p) {
        int s = csr_src[p];
        float w = csr_w[p];
        ushort4 v = *reinterpret_cast<const ushort4*>(&hwb[(size_t)s * HID + lane * 4]);
        a0.x = fmaf(b2f(v.x), w, a0.x); a0.y = fmaf(b2f(v.y), w, a0.y);
        a0.z = fmaf(b2f(v.z), w, a0.z); a0.w = fmaf(b2f(v.w), w, a0.w);
    }
    float4 b4 = reinterpret_cast<const float4*>(bias)[lane];
    float ox = fmaxf(a0.x + a1.x + a2.x + a3.x + b4.x, 0.0f);
    float oy = fmaxf(a0.y + a1.y + a2.y + a3.y + b4.y, 0.0f);
    float oz = fmaxf(a0.z + a1.z + a2.z + a3.z + b4.z, 0.0f);
    float ow = fmaxf(a0.w + a1.w + a2.w + a3.w + b4.w, 0.0f);
    ushort4 hv, lv;
    hv.x = f2b(ox); lv.x = f2b(ox - b2f(hv.x));
    hv.y = f2b(oy); lv.y = f2b(oy - b2f(hv.y));
    hv.z = f2b(oz); lv.z = f2b(oz - b2f(hv.z));
    hv.w = f2b(ow); lv.w = f2b(ow - b2f(hv.w));
    *reinterpret_cast<ushort4*>(&g_hi[(size_t)node * HID + lane * 4]) = hv;
    *reinterpret_cast<ushort4*>(&g_lo[(size_t)node * HID + lane * 4]) = lv;
}

// ---------------- fused sequential GRU ----------------

// Full fused variant (fallback when ws too small for gi8): both GEMMs per step.
__global__ __launch_bounds__(256)
void gru_fused2(const u16* __restrict__ g_hi, const u16* __restrict__ g_lo,
                const u16* __restrict__ h_hi, const u16* __restrict__ h_lo,
                const u16* __restrict__ WihT_hi, const u16* __restrict__ WihT_lo,
                const u16* __restrict__ WhhT_hi, const u16* __restrict__ WhhT_lo,
                const float* __restrict__ b_ih, const float* __restrict__ b_hh,
                float* __restrict__ h, u16* __restrict__ h_hi_o, u16* __restrict__ h_lo_o,
                int n) {
    __shared__ u16 lds[4][32 * 128];
    const int tid  = threadIdx.x;
    const int row0 = blockIdx.x * 32;

    #pragma unroll
    for (int it = 0; it < 2; ++it) {
        int unit = tid + it * 256;
        int r = unit >> 4, s = unit & 15;
        int gr = row0 + r;
        uint4 vg = make_uint4(0,0,0,0), vG = vg, vh = vg, vH = vg;
        if (gr < n) {
            size_t goff = (size_t)gr * 128 + s * 8;
            vg = *reinterpret_cast<const uint4*>(&g_hi[goff]);
            vG = *reinterpret_cast<const uint4*>(&g_lo[goff]);
            vh = *reinterpret_cast<const uint4*>(&h_hi[goff]);
            vH = *reinterpret_cast<const uint4*>(&h_lo[goff]);
        }
        int byte = (r * 256 + s * 16) ^ ((r & 7) << 4);
        *reinterpret_cast<uint4*>((char*)(&lds[0][0]) + byte) = vg;
        *reinterpret_cast<uint4*>((char*)(&lds[1][0]) + byte) = vG;
        *reinterpret_cast<uint4*>((char*)(&lds[2][0]) + byte) = vh;
        *reinterpret_cast<uint4*>((char*)(&lds[3][0]) + byte) = vH;
    }
    __syncthreads();

    const int wid  = tid >> 6;
    const int lane = tid & 63;
    const int l15  = lane & 15;
    const int lkh  = lane >> 4;

    f32x4_t agi[3][2][2] = {};
    f32x4_t agh[3][2][2] = {};

    #pragma unroll
    for (int kb = 0; kb < 4; ++kb) {
        bf16x8_t Agh[2], Agl[2], Ahh[2], Ahl[2];
        #pragma unroll
        for (int m = 0; m < 2; ++m) {
            int row = m * 16 + l15;
            int byte = (row * 256 + kb * 64 + lkh * 16) ^ ((row & 7) << 4);
            Agh[m] = *reinterpret_cast<const bf16x8_t*>((const char*)(&lds[0][0]) + byte);
            Agl[m] = *reinterpret_cast<const bf16x8_t*>((const char*)(&lds[1][0]) + byte);
            Ahh[m] = *reinterpret_cast<const bf16x8_t*>((const char*)(&lds[2][0]) + byte);
            Ahl[m] = *reinterpret_cast<const bf16x8_t*>((const char*)(&lds[3][0]) + byte);
        }
        #pragma unroll
        for (int gt = 0; gt < 3; ++gt) {
            #pragma unroll
            for (int nf = 0; nf < 2; ++nf) {
                int col = gt * HID + wid * 32 + nf * 16 + l15;
                size_t off = (size_t)col * 128 + kb * 32 + lkh * 8;
                bf16x8_t bih = *reinterpret_cast<const bf16x8_t*>(&WihT_hi[off]);
                bf16x8_t bil = *reinterpret_cast<const bf16x8_t*>(&WihT_lo[off]);
                bf16x8_t bhh = *reinterpret_cast<const bf16x8_t*>(&WhhT_hi[off]);
                bf16x8_t bhl = *reinterpret_cast<const bf16x8_t*>(&WhhT_lo[off]);
                #pragma unroll
                for (int m = 0; m < 2; ++m) {
                    agi[gt][m][nf] = __builtin_amdgcn_mfma_f32_16x16x32_bf16(Agh[m], bih, agi[gt][m][nf], 0, 0, 0);
                    agi[gt][m][nf] = __builtin_amdgcn_mfma_f32_16x16x32_bf16(Agh[m], bil, agi[gt][m][nf], 0, 0, 0);
                    agi[gt][m][nf] = __builtin_amdgcn_mfma_f32_16x16x32_bf16(Agl[m], bih, agi[gt][m][nf], 0, 0, 0);
                    agh[gt][m][nf] = __builtin_amdgcn_mfma_f32_16x16x32_bf16(Ahh[m], bhh, agh[gt][m][nf], 0, 0, 0);
                    agh[gt][m][nf] = __builtin_amdgcn_mfma_f32_16x16x32_bf16(Ahh[m], bhl, agh[gt][m][nf], 0, 0, 0);
                    agh[gt][m][nf] = __builtin_amdgcn_mfma_f32_16x16x32_bf16(Ahl[m], bhh, agh[gt][m][nf], 0, 0, 0);
                }
            }
        }
    }

    #pragma unroll
    for (int nf = 0; nf < 2; ++nf) {
        int col = wid * 32 + nf * 16 + l15;
        float bir = b_ih[col], biz = b_ih[HID + col], bin_ = b_ih[2 * HID + col];
        float bhr = b_hh[col], bhz = b_hh[HID + col], bhn = b_hh[2 * HID + col];
        #pragma unroll
        for (int m = 0; m < 2; ++m) {
            #pragma unroll
            for (int r2 = 0; r2 < 4; ++r2) {
                int grow = row0 + m * 16 + lkh * 4 + r2;
                if (grow >= n) continue;
                float rr = sigmoidf_((agi[0][m][nf][r2] + bir) + (agh[0][m][nf][r2] + bhr));
                float zz = sigmoidf_((agi[1][m][nf][r2] + biz) + (agh[1][m][nf][r2] + bhz));
                float nn2 = tanhf((agi[2][m][nf][r2] + bin_) + rr * (agh[2][m][nf][r2] + bhn));
                size_t off = (size_t)grow * HID + col;
                float hold = h[off];
                float hnew = (1.0f - zz) * nn2 + zz * hold;
                h[off] = hnew;
                u16 hv = f2b(hnew);
                h_hi_o[off] = hv;
                h_lo_o[off] = f2b(hnew - b2f(hv));
            }
        }
    }
}

// Slim fused variant: gh = h@W_hh only (gi precomputed in gi8), gates, h update.
// Per 32-row block, 4 waves; wave w owns HID cols [32w,32w+32). 144 MFMA/wave.
__global__ __launch_bounds__(256)
void gru_fused3(const float* __restrict__ gi8t,
                const u16* __restrict__ h_hi, const u16* __restrict__ h_lo,
                const u16* __restrict__ WhhT_hi, const u16* __restrict__ WhhT_lo,
                const float* __restrict__ b_ih, const float* __restrict__ b_hh,
                float* __restrict__ h, u16* __restrict__ h_hi_o, u16* __restrict__ h_lo_o,
                int n) {
    __shared__ u16 lds[2][32 * 128];   // [hhi|hlo], XOR-swizzled; 16 KB
    const int tid  = threadIdx.x;
    const int row0 = blockIdx.x * 32;

    #pragma unroll
    for (int it = 0; it < 2; ++it) {
        int unit = tid + it * 256;
        int r = unit >> 4, s = unit & 15;
        int gr = row0 + r;
        uint4 vh = make_uint4(0,0,0,0), vH = vh;
        if (gr < n) {
            size_t goff = (size_t)gr * 128 + s * 8;
            vh = *reinterpret_cast<const uint4*>(&h_hi[goff]);
            vH = *reinterpret_cast<const uint4*>(&h_lo[goff]);
        }
        int byte = (r * 256 + s * 16) ^ ((r & 7) << 4);
        *reinterpret_cast<uint4*>((char*)(&lds[0][0]) + byte) = vh;
        *reinterpret_cast<uint4*>((char*)(&lds[1][0]) + byte) = vH;
    }
    __syncthreads();

    const int wid  = tid >> 6;
    const int lane = tid & 63;
    const int l15  = lane & 15;
    const int lkh  = lane >> 4;

    f32x4_t agh[3][2][2] = {};   // [gate][m][nf]

    #pragma unroll
    for (int kb = 0; kb < 4; ++kb) {
        bf16x8_t Ahh[2], Ahl[2];
        #pragma unroll
        for (int m = 0; m < 2; ++m) {
            int row = m * 16 + l15;
            int byte = (row * 256 + kb * 64 + lkh * 16) ^ ((row & 7) << 4);
            Ahh[m] = *reinterpret_cast<const bf16x8_t*>((const char*)(&lds[0][0]) + byte);
            Ahl[m] = *reinterpret_cast<const bf16x8_t*>((const char*)(&lds[1][0]) + byte);
        }
        #pragma unroll
        for (int gt = 0; gt < 3; ++gt) {
            #pragma unroll
            for (int nf = 0; nf < 2; ++nf) {
                int col = gt * HID + wid * 32 + nf * 16 + l15;
                size_t off = (size_t)col * 128 + kb * 32 + lkh * 8;
                bf16x8_t bhh = *reinterpret_cast<const bf16x8_t*>(&WhhT_hi[off]);
                bf16x8_t bhl = *reinterpret_cast<const bf16x8_t*>(&WhhT_lo[off]);
                #pragma unroll
                for (int m = 0; m < 2; ++m) {
                    agh[gt][m][nf] = __builtin_amdgcn_mfma_f32_16x16x32_bf16(Ahh[m], bhh, agh[gt][m][nf], 0, 0, 0);
                    agh[gt][m][nf] = __builtin_amdgcn_mfma_f32_16x16x32_bf16(Ahh[m], bhl, agh[gt][m][nf], 0, 0, 0);
                    agh[gt][m][nf] = __builtin_amdgcn_mfma_f32_16x16x32_bf16(Ahl[m], bhh, agh[gt][m][nf], 0, 0, 0);
                }
            }
        }
    }

    #pragma unroll
    for (int nf = 0; nf < 2; ++nf) {
        int col = wid * 32 + nf * 16 + l15;
        float bir = b_ih[col], biz = b_ih[HID + col], bin_ = b_ih[2 * HID + col];
        float bhr = b_hh[col], bhz = b_hh[HID + col], bhn = b_hh[2 * HID + col];
        #pragma unroll
        for (int m = 0; m < 2; ++m) {
            #pragma unroll
            for (int r2 = 0; r2 < 4; ++r2) {
                int grow = row0 + m * 16 + lkh * 4 + r2;
                if (grow >= n) continue;
                size_t gbase = (size_t)grow * H3 + col;
                float gir = gi8t[gbase];
                float giz = gi8t[gbase + HID];
                float gin = gi8t[gbase + 2 * HID];
                float rr = sigmoidf_((gir + bir) + (agh[0][m][nf][r2] + bhr));
                float zz = sigmoidf_((giz + biz) + (agh[1][m][nf][r2] + bhz));
                float nn2 = tanhf((gin + bin_) + rr * (agh[2][m][nf][r2] + bhn));
                size_t off = (size_t)grow * HID + col;
                float hold = h[off];
                float hnew = (1.0f - zz) * nn2 + zz * hold;
                h[off] = hnew;
                u16 hv = f2b(hnew);
                h_hi_o[off] = hv;
                h_lo_o[off] = f2b(hnew - b2f(hv));
            }
        }
    }
}

// ---------------- launcher ----------------

extern "C" void kernel_launch(void* const* d_in, const int* in_sizes, int n_in,
                              void* d_out, int out_size, void* d_ws, size_t ws_size,
                              hipStream_t stream) {
    const float* x        = (const float*)d_in[0];
    const float* edge_attr= (const float*)d_in[1];
    const float* W_lin    = (const float*)d_in[2];
    const float* b_lin    = (const float*)d_in[3];
    const float* Wc1      = (const float*)d_in[4];
    const float* bc1      = (const float*)d_in[5];
    const float* Wc2      = (const float*)d_in[6];
    const float* bc2      = (const float*)d_in[7];
    const float* W_ih     = (const float*)d_in[8];
    const float* b_ih     = (const float*)d_in[9];
    const float* W_hh     = (const float*)d_in[10];
    const float* b_hh     = (const float*)d_in[11];
    const float* Wf1      = (const float*)d_in[12];
    const float* bf1      = (const float*)d_in[13];
    const float* Wf2      = (const float*)d_in[14];
    const float* bf2      = (const float*)d_in[15];
    const float* Wg1      = (const float*)d_in[16];
    const float* bg1      = (const float*)d_in[17];
    const float* Wg2      = (const float*)d_in[18];
    const float* bg2      = (const float*)d_in[19];
    const int*   edge_index = (const int*)d_in[20];
    const int*   mask     = (const int*)d_in[21];

    const int n = in_sizes[21];       // 20000
    const int e = in_sizes[1];        // 320000
    const int* src = edge_index;
    const int* dst = edge_index + e;
    float* h = (float*)d_out;         // [n,128], GRU state (fp32)

    char* w = (char*)d_ws;
    auto alloc = [&](size_t bytes) -> char* {
        char* p = w;
        w += (bytes + 255) & ~(size_t)255;
        return p;
    };
    int*   first_eid = (int*)  alloc((size_t)n * 4);
    int*   deg_cnt   = (int*)  alloc((size_t)n * 4);
    int*   row_ptr   = (int*)  alloc((size_t)(n + 1) * 4);
    int*   fill_ptr  = (int*)  alloc((size_t)n * 4);
    int*   tmp_scan  = (int*)  alloc((size_t)n * 4);
    int*   bsum      = (int*)  alloc((size_t)256 * 4);
    float* dis       = (float*)alloc((size_t)n * 4);
    float* norm_self = (float*)alloc((size_t)n * 4);
    int*   first_out = (int*)  alloc((size_t)n * 4);
    float* first_dx  = (float*)alloc((size_t)n * 4);
    int*   d1_of     = (int*)  alloc((size_t)n * 4);
    int*   d2_of     = (int*)  alloc((size_t)n * 4);
    float* dxb_of    = (float*)alloc((size_t)n * 4);
    int*   ghost_list= (int*)  alloc((size_t)n * 4);
    int*   ghost_pos = (int*)  alloc((size_t)n * 4);
    int*   gcount    = (int*)  alloc(256);
    int*   csr_src   = (int*)  alloc((size_t)e * 4);
    float* csr_w     = (float*)alloc((size_t)e * 4);
    // bf16 split weight transposes BT[n][k]
    u16* Wc1T_hi = (u16*)alloc((size_t)HID * 128 * 2);
    u16* Wc1T_lo = (u16*)alloc((size_t)HID * 128 * 2);
    u16* Wc2T_hi = (u16*)alloc((size_t)HID * 128 * 2);
    u16* Wc2T_lo = (u16*)alloc((size_t)HID * 128 * 2);
    u16* WihT_hi = (u16*)alloc((size_t)H3 * 128 * 2);
    u16* WihT_lo = (u16*)alloc((size_t)H3 * 128 * 2);
    u16* WhhT_hi = (u16*)alloc((size_t)H3 * 128 * 2);
    u16* WhhT_lo = (u16*)alloc((size_t)H3 * 128 * 2);
    // activations (batched over all T_IN)
    u16*   g8_hi = (u16*)  alloc((size_t)T_IN * n * HID * 2);   // 41 MB
    u16*   g8_lo = (u16*)  alloc((size_t)T_IN * n * HID * 2);   // 41 MB
    u16*   bufHb = (u16*)  alloc((size_t)T_IN * n * HID * 2);   // 41 MB
    float* xf_buf= (float*)alloc((size_t)n * T_IN * FEAT * 4);  // 10 MB
    u16*   h_hi  = (u16*)  alloc((size_t)n * HID * 2);
    u16*   h_lo  = (u16*)  alloc((size_t)n * HID * 2);
    // optional: gi8 (fp32, all t) — only if workspace is large enough
    size_t gi8_bytes = (size_t)T_IN * n * H3 * 4;               // 246 MB
    size_t used = (size_t)(w - (char*)d_ws);
    bool use_gi8 = (used + gi8_bytes + 256) <= ws_size;
    float* gi8 = use_gi8 ? (float*)alloc(gi8_bytes) : nullptr;

    const int TPB = 256;
    const int nb = (n + 255) / 256;
    dim3 gN(nb), gE((e + TPB - 1) / TPB);

    // preprocessing (time-invariant)
    init_kernel<<<gN, TPB, 0, stream>>>(first_eid, deg_cnt, gcount, n);
    edge_pass1<<<gE, TPB, 0, stream>>>(src, dst, first_eid, deg_cnt, e);
    scan1<<<gN, TPB, 0, stream>>>(deg_cnt, tmp_scan, bsum, n);
    scan2<<<1, TPB, 0, stream>>>(bsum, nb);
    scan3<<<gN, TPB, 0, stream>>>(deg_cnt, tmp_scan, bsum, row_ptr, fill_ptr, dis, norm_self, n);
    firsts_kernel<<<gN, TPB, 0, stream>>>(first_eid, dst, edge_attr, first_out, first_dx, n, e);
    edge_pass2<<<gE, TPB, 0, stream>>>(src, dst, fill_ptr, dis, csr_src, csr_w, e);
    ghost_kernel<<<gN, TPB, 0, stream>>>(mask, first_out, first_dx, d1_of, d2_of, dxb_of,
                                         ghost_list, ghost_pos, gcount, n);
    wsplit_kernel<<<dim3(HID / 32, 4), TPB, 0, stream>>>(Wc1, Wc1T_hi, Wc1T_lo, HID);
    wsplit_kernel<<<dim3(HID / 32, 4), TPB, 0, stream>>>(Wc2, Wc2T_hi, Wc2T_lo, HID);
    wsplit_kernel<<<dim3(H3 / 32, 4), TPB, 0, stream>>>(W_ih, WihT_hi, WihT_lo, H3);
    wsplit_kernel<<<dim3(H3 / 32, 4), TPB, 0, stream>>>(W_hh, WhhT_hi, WhhT_lo, H3);

    // h0 = 0 (fp32) and split hi/lo (adjacent region, as u32 words)
    zero2_kernel<<<2048, TPB, 0, stream>>>(h, n * HID, (unsigned*)h_hi, n * HID);

    // ---- Phase A: front end for ALL timesteps (independent of h) ----
    fuse_ghost<<<dim3(n, T_IN), 128, 0, stream>>>(x, ghost_list, gcount, d1_of, d2_of, dxb_of,
                                                  Wf1, bf1, Wf2, bf2, Wg1, bg1, Wg2, bg2,
                                                  xf_buf);
    lin_all<<<2048, 256, 0, stream>>>(x, xf_buf, ghost_pos, W_lin, b_lin,
                                      g8_hi, g8_lo, n, n * T_IN);
    dim3 grid_gcn((n + 63) / 64, 1, T_IN);
    const int agg_blocks = ((n + 7) / 8) * T_IN;    // t = bid & 7 (XCD affinity)
    gemm_gcn_b<<<grid_gcn, 256, 0, stream>>>(g8_hi, g8_lo, Wc1T_hi, Wc1T_lo, bufHb, n);
    gcn_agg_b<<<agg_blocks, 256, 0, stream>>>(bufHb, row_ptr, csr_src, csr_w,
                                              norm_self, bc1, g8_hi, g8_lo, n);
    gemm_gcn_b<<<grid_gcn, 256, 0, stream>>>(g8_hi, g8_lo, Wc2T_hi, Wc2T_lo, bufHb, n);
    gcn_agg_b<<<agg_blocks, 256, 0, stream>>>(bufHb, row_ptr, csr_src, csr_w,
                                              norm_self, bc2, g8_hi, g8_lo, n);

    // ---- Phase B: sequential GRU over timesteps ----
    const int gru_blocks = (n + 31) / 32;
    if (use_gi8) {
        // batched gi = G_t @ W_ih for all t (h-independent), then slim per-step gh+gates
        dim3 grid_gi((n + 63) / 64, 3, T_IN);
        gemm_gi_b<<<grid_gi, 256, 0, stream>>>(g8_hi, g8_lo, WihT_hi, WihT_lo, gi8, n);
        for (int t = 0; t < T_IN; ++t) {
            const float* gi8t = gi8 + (size_t)t * n * H3;
            gru_fused3<<<gru_blocks, 256, 0, stream>>>(gi8t, h_hi, h_lo,
                                                       WhhT_hi, WhhT_lo,
                                                       b_ih, b_hh, h, h_hi, h_lo, n);
        }
    } else {
        for (int t = 0; t < T_IN; ++t) {
            const u16* Gt_hi = g8_hi + (size_t)t * n * HID;
            const u16* Gt_lo = g8_lo + (size_t)t * n * HID;
            gru_fused2<<<gru_blocks, 256, 0, stream>>>(Gt_hi, Gt_lo, h_hi, h_lo,
                                                       WihT_hi, WihT_lo, WhhT_hi, WhhT_lo,
                                                       b_ih, b_hh, h, h_hi, h_lo, n);
        }
    }
}